// Round 2
// baseline (312.435 us; speedup 1.0000x reference)
//
#include <hip/hip_runtime.h>

#define EPS 1e-5f
#define B 16
#define CH 22
#define T_IN 1001
#define F 36
#define RF 65
#define T1 937            // T_IN - RF + 1
#define TT 16             // K1 t-tile
#define NT 59             // ceil(937/16)
#define XS_P 81           // padded x row stride (odd -> <=2-way banks)
#define HS 796            // h1s row stride in floats (mult of 4, 28t%32 -> 2-way)
#define HS4 199           // HS/4
#define UN 885            // valid u range for Q/E
#define UT 64             // K2 u-tile
#define NU 14             // ceil(885/64)
#define PS_LEN 106        // UT-1 + 3*14 + 1
#define KS 15
#define GN 295
#define WN 129
#define M43 43

#define H2_OFF 0
#define E_OFF  539712     // 16*36*937
#define S_OFF  1049472    // E_OFF + 16*36*885

__device__ __forceinline__ float elu_f(float v) {
    return v > 0.f ? v : (__expf(v) - 1.f);
}

// ---------------- K1: temporal conv + bn + elu + spatial conv + bn + elu ----
// 192 threads: temporal = items (fi,ch,t-half); spatial = 16 t x 12 fog x 3 fo
__global__ __launch_bounds__(192) void k_front(
    const float* __restrict__ x,   const float* __restrict__ w_t,
    const float* __restrict__ b_t, const float* __restrict__ g_t,
    const float* __restrict__ be_t,const float* __restrict__ m_t,
    const float* __restrict__ v_t, const float* __restrict__ w_s,
    const float* __restrict__ b_s, const float* __restrict__ g_s,
    const float* __restrict__ be_s,const float* __restrict__ m_s,
    const float* __restrict__ v_s, float* __restrict__ h2)
{
    __shared__ float xs[CH * XS_P];                 // 7.1 KB
    __shared__ __align__(16) float h1s[TT * HS];    // 49.8 KB, layout [t][fc]
    __shared__ float wts[F * RF];                   // 9.4 KB
    __shared__ float st[F], ot[F], ss[F], os[F];

    const int tid = threadIdx.x;
    const int b  = blockIdx.y;
    const int t0 = blockIdx.x * TT;

    for (int i = tid; i < CH * XS_P; i += 192) {
        int ch = i / XS_P, j = i % XS_P;
        int t = t0 + j;
        float v = 0.f;
        if (j < TT + RF - 1 && t < T_IN) v = x[(b * CH + ch) * T_IN + t];
        xs[i] = v;
    }
    for (int i = tid; i < F * RF; i += 192) wts[i] = w_t[i];
    if (tid < F) {
        float s1 = g_t[tid] * rsqrtf(v_t[tid] + EPS);
        st[tid] = s1; ot[tid] = (b_t[tid] - m_t[tid]) * s1 + be_t[tid];
        float s2 = g_s[tid] * rsqrtf(v_s[tid] + EPS);
        ss[tid] = s2; os[tid] = (b_s[tid] - m_s[tid]) * s2 + be_s[tid];
    }
    __syncthreads();

    // temporal conv: rolling register window, full unroll -> shifts are renames
    for (int it = tid; it < F * CH * 2; it += 192) {
        int th = it & 1, fc = it >> 1;
        int ch = fc % CH, fi = fc / CH;
        const float* xr = &xs[ch * XS_P + th * 8];
        const float* wr = &wts[fi * RF];
        float xw[8], acc[8];
        #pragma unroll
        for (int j = 0; j < 8; ++j) { xw[j] = xr[j]; acc[j] = 0.f; }
        #pragma unroll
        for (int k = 0; k < RF; ++k) {
            float wv = wr[k];
            #pragma unroll
            for (int j = 0; j < 8; ++j) acc[j] += xw[j] * wv;
            if (k < RF - 1) {
                #pragma unroll
                for (int j = 0; j < 7; ++j) xw[j] = xw[j + 1];
                xw[7] = xr[k + 8];
            }
        }
        float sc = st[fi], of = ot[fi];
        #pragma unroll
        for (int j = 0; j < 8; ++j) {
            float v2 = acc[j] * sc + of;
            h1s[(th * 8 + j) * HS + fc] = elu_f(v2);
        }
    }
    __syncthreads();

    // spatial conv: thread = (t, fog); 3 consecutive fo per fog, balanced
    {
        const int t = tid & 15, fog = tid >> 4;      // fog in [0,12)
        const int fo0 = fog * 3;
        const float4* hr = (const float4*)h1s + t * HS4;
        const float4* w0 = (const float4*)(w_s + (fo0 + 0) * (F * CH));
        const float4* w1 = (const float4*)(w_s + (fo0 + 1) * (F * CH));
        const float4* w2 = (const float4*)(w_s + (fo0 + 2) * (F * CH));
        float a0 = 0.f, a1 = 0.f, a2 = 0.f;
        for (int q = 0; q < (F * CH) / 4; ++q) {
            float4 h = hr[q];
            float4 u0v = w0[q], u1v = w1[q], u2v = w2[q];
            a0 += h.x * u0v.x + h.y * u0v.y + h.z * u0v.z + h.w * u0v.w;
            a1 += h.x * u1v.x + h.y * u1v.y + h.z * u1v.z + h.w * u1v.w;
            a2 += h.x * u2v.x + h.y * u2v.y + h.z * u2v.z + h.w * u2v.w;
        }
        int t_g = t0 + t;
        if (t_g < T1) {
            float vA = elu_f(a0 * ss[fo0]     + os[fo0]);
            float vB = elu_f(a1 * ss[fo0 + 1] + os[fo0 + 1]);
            float vC = elu_f(a2 * ss[fo0 + 2] + os[fo0 + 2]);
            h2[(b * F + fo0)     * T1 + t_g] = vA;
            h2[(b * F + fo0 + 1) * T1 + t_g] = vB;
            h2[(b * F + fo0 + 2) * T1 + t_g] = vC;
        }
    }
}

// ---------------- K2: pooled dilated conv Q + bn + elu -> E -----------------
// 512 threads = 8 waves; wave g handles 4-5 fo; weights via wave-uniform
// (scalarized) global loads, only Ps lives in LDS.
__global__ __launch_bounds__(512) void k_qconv(
    const float* __restrict__ h2, const float* __restrict__ w_c,
    const float* __restrict__ b_c, const float* __restrict__ g_c,
    const float* __restrict__ be_c, const float* __restrict__ m_c,
    const float* __restrict__ v_c, float* __restrict__ E)
{
    __shared__ float Ps[F * PS_LEN];   // 15.3 KB
    const int tid = threadIdx.x;
    const int b  = blockIdx.y;
    const int u0 = blockIdx.x * UT;

    for (int i = tid; i < F * PS_LEN; i += 512) {
        int f = i / PS_LEN, j = i % PS_LEN;
        int s = u0 + j;
        const float* hr = h2 + (b * F + f) * T1;
        float a0 = (s     < T1) ? hr[s]     : 0.f;
        float a1 = (s + 1 < T1) ? hr[s + 1] : 0.f;
        float a2 = (s + 2 < T1) ? hr[s + 2] : 0.f;
        Ps[i] = (a0 + a1 + a2) * (1.f / 3.f);
    }
    __syncthreads();

    const int u = tid & 63;
    int g = __builtin_amdgcn_readfirstlane(tid >> 6);   // wave-uniform group
    const int fo_base = (g < 4) ? g * 5 : 20 + (g - 4) * 4;
    const int nfo     = (g < 4) ? 5 : 4;
    const float* wb = w_c + fo_base * (F * KS);         // uniform base -> s_load

    float acc[5];
    #pragma unroll
    for (int j = 0; j < 5; ++j) acc[j] = 0.f;

    for (int f = 0; f < F; ++f) {
        const int pb = f * PS_LEN + u;
        const int wf = f * KS;
        #pragma unroll
        for (int k = 0; k < KS; ++k) {
            float pv = Ps[pb + 3 * k];
            #pragma unroll
            for (int j = 0; j < 5; ++j)
                if (j < nfo) acc[j] += pv * wb[j * (F * KS) + wf + k];
        }
    }
    int u_g = u0 + u;
    if (u_g < UN) {
        #pragma unroll
        for (int j = 0; j < 5; ++j) {
            if (j < nfo) {
                int fo = fo_base + j;
                float s  = g_c[fo] * rsqrtf(v_c[fo] + EPS);
                float v2 = (acc[j] + b_c[fo] - m_c[fo]) * s + be_c[fo];
                E[(b * F + fo) * UN + u_g] = elu_f(v2);
            }
        }
    }
}

// ---------------- K3: crop-sum window sums -> S -----------------------------
__global__ __launch_bounds__(256) void k_wins(
    const float* __restrict__ E, float* __restrict__ S)
{
    __shared__ float Es[UN];
    __shared__ float G[GN];
    __shared__ float Ws[WN];
    const int tid = threadIdx.x;
    const int bf = blockIdx.x;
    const float* er = E + bf * UN;
    for (int i = tid; i < UN; i += 256) Es[i] = er[i];
    __syncthreads();
    for (int q = tid; q < GN; q += 256)
        G[q] = Es[3 * q] + Es[3 * q + 1] + Es[3 * q + 2];
    __syncthreads();
    if (tid < WN) {
        float a = 0.f;
        for (int q = tid; q < tid + 167; ++q) a += G[q];
        Ws[tid] = a;
    }
    __syncthreads();
    if (tid < M43)
        S[bf * M43 + tid] = (Ws[3 * tid] + Ws[3 * tid + 1] + Ws[3 * tid + 2]) * (1.f / 3.f);
}

// ---------------- K4: FC over summed features -------------------------------
__global__ __launch_bounds__(256) void k_fc(
    const float* __restrict__ S, const float* __restrict__ w_fc,
    const float* __restrict__ b_fc, float* __restrict__ out)
{
    const int b = blockIdx.x;
    const int o = threadIdx.x >> 6;
    const int lane = threadIdx.x & 63;
    float acc = 0.f;
    for (int n = lane; n < F * M43; n += 64)
        acc += w_fc[o * (F * M43) + n] * S[b * (F * M43) + n];
    #pragma unroll
    for (int off = 32; off > 0; off >>= 1)
        acc += __shfl_down(acc, off, 64);
    if (lane == 0) out[b * 4 + o] = acc * (1.f / 501.f) + b_fc[o];
}

extern "C" void kernel_launch(void* const* d_in, const int* in_sizes, int n_in,
                              void* d_out, int out_size, void* d_ws, size_t ws_size,
                              hipStream_t stream) {
    const float* x    = (const float*)d_in[0];
    const float* w_t  = (const float*)d_in[1];
    const float* b_t  = (const float*)d_in[2];
    const float* g_t  = (const float*)d_in[3];
    const float* be_t = (const float*)d_in[4];
    const float* m_t  = (const float*)d_in[5];
    const float* v_t  = (const float*)d_in[6];
    const float* w_s  = (const float*)d_in[7];
    const float* b_s  = (const float*)d_in[8];
    const float* g_s  = (const float*)d_in[9];
    const float* be_s = (const float*)d_in[10];
    const float* m_s  = (const float*)d_in[11];
    const float* v_s  = (const float*)d_in[12];
    const float* w_c  = (const float*)d_in[13];
    const float* b_c  = (const float*)d_in[14];
    const float* g_c  = (const float*)d_in[15];
    const float* be_c = (const float*)d_in[16];
    const float* m_c  = (const float*)d_in[17];
    const float* v_c  = (const float*)d_in[18];
    const float* w_fc = (const float*)d_in[19];
    const float* b_fc = (const float*)d_in[20];

    float* ws = (float*)d_ws;
    float* h2 = ws + H2_OFF;
    float* E  = ws + E_OFF;
    float* S  = ws + S_OFF;
    float* out = (float*)d_out;

    k_front<<<dim3(NT, B), 192, 0, stream>>>(x, w_t, b_t, g_t, be_t, m_t, v_t,
                                             w_s, b_s, g_s, be_s, m_s, v_s, h2);
    k_qconv<<<dim3(NU, B), 512, 0, stream>>>(h2, w_c, b_c, g_c, be_c, m_c, v_c, E);
    k_wins<<<B * F, 256, 0, stream>>>(E, S);
    k_fc<<<B, 256, 0, stream>>>(S, w_fc, b_fc, out);
}

// Round 3
// 283.198 us; speedup vs baseline: 1.1032x; 1.1032x over previous
//
#include <hip/hip_runtime.h>

#define EPS 1e-5f
#define B 16
#define CH 22
#define T_IN 1001
#define F 36
#define RF 65
#define T1 937            // T_IN - RF + 1
#define FC 792            // F*CH
#define UN 885            // valid u range for Q/E
#define UT 64             // K2 u-tile
#define NU 14             // ceil(885/64)
#define PS_LEN 106        // UT-1 + 3*14 + 1
#define KS 15
#define GN 295
#define WN 129
#define M43 43

// workspace float offsets
#define H2_OFF  0
#define E_OFF   539712            // + 16*36*937
#define S_OFF   1049472           // + 16*36*885
#define WTT_OFF 1074240           // + 16*36*43
#define WST_OFF 1076580           // + 65*36
#define WCT_OFF 1105092           // + 792*36
#define H1_OFF  1124544           // + 36*15*36 (rounded to 64)

__device__ __forceinline__ float elu_f(float v) {
    return v > 0.f ? v : (__expf(v) - 1.f);
}

// ---- prep: transpose weights for wave-uniform scalar access ---------------
__global__ __launch_bounds__(256) void k_prep(
    const float* __restrict__ w_t, const float* __restrict__ w_s,
    const float* __restrict__ w_c, float* __restrict__ wtT,
    float* __restrict__ wsT, float* __restrict__ wcT)
{
    int i = blockIdx.x * 256 + threadIdx.x;
    if (i < F * RF)     { int k = i / F,  fi = i % F; wtT[i] = w_t[fi * RF + k]; }
    if (i < FC * F)     { int fc = i / F, fo = i % F; wsT[i] = w_s[fo * FC + fc]; }
    if (i < F * KS * F) { int fk = i / F, fo = i % F; int f = fk / KS, k = fk % KS;
                          wcT[i] = w_c[(fo * F + f) * KS + k]; }
}

// ---- K1a: temporal conv + bn + elu -> h1[b][fc][t] (slab) -----------------
// grid (ntw, CH, B); 256 thr = 4 waves; wave = 9 fi x 64 t (lane = t)
__global__ __launch_bounds__(256) void k_tconv(
    const float* __restrict__ x,   const float* __restrict__ wtT,
    const float* __restrict__ b_t, const float* __restrict__ g_t,
    const float* __restrict__ be_t,const float* __restrict__ m_t,
    const float* __restrict__ v_t, float* __restrict__ h1,
    int t_base, int TS, int TSeff)
{
    const int lane = threadIdx.x & 63;
    const int fi0  = __builtin_amdgcn_readfirstlane((threadIdx.x >> 6) * 9);
    const int b = blockIdx.z, ch = blockIdx.y;
    const int tloc = blockIdx.x * 64 + lane;
    const int t  = t_base + tloc;
    const int tc = t < (T1 - 1) ? t : (T1 - 1);
    const float* xr = x + (b * CH + ch) * T_IN + tc;

    float acc[9];
    #pragma unroll
    for (int j = 0; j < 9; ++j) acc[j] = 0.f;

    #pragma unroll 5
    for (int k = 0; k < RF; ++k) {
        float xv = xr[k];
        const float* wr = wtT + k * F + fi0;
        #pragma unroll
        for (int j = 0; j < 9; ++j) acc[j] += xv * wr[j];
    }

    if (t < T1 && tloc < TSeff) {
        #pragma unroll
        for (int j = 0; j < 9; ++j) {
            int fi = fi0 + j;
            float s1 = g_t[fi] * rsqrtf(v_t[fi] + EPS);
            float o1 = (b_t[fi] - m_t[fi]) * s1 + be_t[fi];
            h1[((size_t)(b * F + fi) * CH + ch) * TS + tloc] =
                elu_f(acc[j] * s1 + o1);
        }
    }
}

// ---- K1b: 1x1 spatial conv (K=792 dot) + bn + elu -> h2[b][fo][t] ---------
// grid (ntw, B); 384 thr = 6 waves; wave = 6 fo x 64 t (lane = t)
__global__ __launch_bounds__(384) void k_sconv(
    const float* __restrict__ h1,  const float* __restrict__ wsT,
    const float* __restrict__ b_s, const float* __restrict__ g_s,
    const float* __restrict__ be_s,const float* __restrict__ m_s,
    const float* __restrict__ v_s, float* __restrict__ h2,
    int t_base, int TS, int TSeff)
{
    const int lane = threadIdx.x & 63;
    const int fo0  = __builtin_amdgcn_readfirstlane((threadIdx.x >> 6) * 6);
    const int b = blockIdx.y;
    const int tloc = blockIdx.x * 64 + lane;
    const int tlc  = tloc < (TSeff - 1) ? tloc : (TSeff - 1);
    const float* hr = h1 + (size_t)b * FC * TS + tlc;

    float acc[6];
    #pragma unroll
    for (int j = 0; j < 6; ++j) acc[j] = 0.f;

    #pragma unroll 4
    for (int fc = 0; fc < FC; ++fc) {
        float hv = hr[(size_t)fc * TS];
        const float* wr = wsT + fc * F + fo0;
        #pragma unroll
        for (int j = 0; j < 6; ++j) acc[j] += hv * wr[j];
    }

    int t = t_base + tloc;
    if (tloc < TSeff && t < T1) {
        #pragma unroll
        for (int j = 0; j < 6; ++j) {
            int fo = fo0 + j;
            float s2 = g_s[fo] * rsqrtf(v_s[fo] + EPS);
            float o2 = (b_s[fo] - m_s[fo]) * s2 + be_s[fo];
            h2[(b * F + fo) * T1 + t] = elu_f(acc[j] * s2 + o2);
        }
    }
}

// ---- K2: pooled dilated conv Q + bn + elu -> E ----------------------------
// grid (NU, B); 256 thr = 4 waves; wave = 9 fo x 64 u (lane = u)
__global__ __launch_bounds__(256) void k_qconv(
    const float* __restrict__ h2,  const float* __restrict__ wcT,
    const float* __restrict__ b_c, const float* __restrict__ g_c,
    const float* __restrict__ be_c,const float* __restrict__ m_c,
    const float* __restrict__ v_c, float* __restrict__ E)
{
    __shared__ float Ps[F * PS_LEN];   // 15.3 KB
    const int tid = threadIdx.x;
    const int b  = blockIdx.y;
    const int u0 = blockIdx.x * UT;

    for (int i = tid; i < F * PS_LEN; i += 256) {
        int f = i / PS_LEN, j = i % PS_LEN;
        int s = u0 + j;
        const float* hr = h2 + (b * F + f) * T1;
        float a0 = (s     < T1) ? hr[s]     : 0.f;
        float a1 = (s + 1 < T1) ? hr[s + 1] : 0.f;
        float a2 = (s + 2 < T1) ? hr[s + 2] : 0.f;
        Ps[i] = (a0 + a1 + a2) * (1.f / 3.f);
    }
    __syncthreads();

    const int u   = tid & 63;
    const int fo0 = __builtin_amdgcn_readfirstlane((tid >> 6) * 9);

    float acc[9];
    #pragma unroll
    for (int j = 0; j < 9; ++j) acc[j] = 0.f;

    for (int f = 0; f < F; ++f) {
        const int pb = f * PS_LEN + u;
        #pragma unroll
        for (int k = 0; k < KS; ++k) {
            float pv = Ps[pb + 3 * k];
            const float* wr = wcT + (f * KS + k) * F + fo0;
            #pragma unroll
            for (int j = 0; j < 9; ++j) acc[j] += pv * wr[j];
        }
    }
    int u_g = u0 + u;
    if (u_g < UN) {
        #pragma unroll
        for (int j = 0; j < 9; ++j) {
            int fo = fo0 + j;
            float s  = g_c[fo] * rsqrtf(v_c[fo] + EPS);
            float v2 = (acc[j] + b_c[fo] - m_c[fo]) * s + be_c[fo];
            E[(b * F + fo) * UN + u_g] = elu_f(v2);
        }
    }
}

// ---- K3: crop-sum window sums -> S ----------------------------------------
__global__ __launch_bounds__(256) void k_wins(
    const float* __restrict__ E, float* __restrict__ S)
{
    __shared__ float Es[UN];
    __shared__ float G[GN];
    __shared__ float Ws[WN];
    const int tid = threadIdx.x;
    const int bf = blockIdx.x;
    const float* er = E + bf * UN;
    for (int i = tid; i < UN; i += 256) Es[i] = er[i];
    __syncthreads();
    for (int q = tid; q < GN; q += 256)
        G[q] = Es[3 * q] + Es[3 * q + 1] + Es[3 * q + 2];
    __syncthreads();
    if (tid < WN) {
        float a = 0.f;
        for (int q = tid; q < tid + 167; ++q) a += G[q];
        Ws[tid] = a;
    }
    __syncthreads();
    if (tid < M43)
        S[bf * M43 + tid] = (Ws[3 * tid] + Ws[3 * tid + 1] + Ws[3 * tid + 2]) * (1.f / 3.f);
}

// ---- K4: FC over summed features ------------------------------------------
__global__ __launch_bounds__(256) void k_fc(
    const float* __restrict__ S, const float* __restrict__ w_fc,
    const float* __restrict__ b_fc, float* __restrict__ out)
{
    const int b = blockIdx.x;
    const int o = threadIdx.x >> 6;
    const int lane = threadIdx.x & 63;
    float acc = 0.f;
    for (int n = lane; n < F * M43; n += 64)
        acc += w_fc[o * (F * M43) + n] * S[b * (F * M43) + n];
    #pragma unroll
    for (int off = 32; off > 0; off >>= 1)
        acc += __shfl_down(acc, off, 64);
    if (lane == 0) out[b * 4 + o] = acc * (1.f / 501.f) + b_fc[o];
}

extern "C" void kernel_launch(void* const* d_in, const int* in_sizes, int n_in,
                              void* d_out, int out_size, void* d_ws, size_t ws_size,
                              hipStream_t stream) {
    const float* x    = (const float*)d_in[0];
    const float* w_t  = (const float*)d_in[1];
    const float* b_t  = (const float*)d_in[2];
    const float* g_t  = (const float*)d_in[3];
    const float* be_t = (const float*)d_in[4];
    const float* m_t  = (const float*)d_in[5];
    const float* v_t  = (const float*)d_in[6];
    const float* w_s  = (const float*)d_in[7];
    const float* b_s  = (const float*)d_in[8];
    const float* g_s  = (const float*)d_in[9];
    const float* be_s = (const float*)d_in[10];
    const float* m_s  = (const float*)d_in[11];
    const float* v_s  = (const float*)d_in[12];
    const float* w_c  = (const float*)d_in[13];
    const float* b_c  = (const float*)d_in[14];
    const float* g_c  = (const float*)d_in[15];
    const float* be_c = (const float*)d_in[16];
    const float* v_c  = (const float*)d_in[18];
    const float* m_c  = (const float*)d_in[17];
    const float* w_fc = (const float*)d_in[19];
    const float* b_fc = (const float*)d_in[20];

    float* ws  = (float*)d_ws;
    float* h2  = ws + H2_OFF;
    float* E   = ws + E_OFF;
    float* S   = ws + S_OFF;
    float* wtT = ws + WTT_OFF;
    float* wsT = ws + WST_OFF;
    float* wcT = ws + WCT_OFF;
    float* h1  = ws + H1_OFF;
    float* out = (float*)d_out;

    // slab the t-dimension so h1 fits whatever scratch we actually have
    long long availF = (long long)(ws_size / 4) - (long long)H1_OFF;
    long long tsl = availF / (B * FC);
    int TS;
    if (tsl >= T1) TS = T1;
    else { TS = (int)(tsl & ~63LL); if (TS < 64) TS = 64; }
    int nslab = (T1 + TS - 1) / TS;

    k_prep<<<dim3(112), 256, 0, stream>>>(w_t, w_s, w_c, wtT, wsT, wcT);

    for (int sl = 0; sl < nslab; ++sl) {
        int t_base = sl * TS;
        int TSeff = T1 - t_base; if (TSeff > TS) TSeff = TS;
        int ntw = (TSeff + 63) / 64;
        k_tconv<<<dim3(ntw, CH, B), 256, 0, stream>>>(
            x, wtT, b_t, g_t, be_t, m_t, v_t, h1, t_base, TS, TSeff);
        k_sconv<<<dim3(ntw, B), 384, 0, stream>>>(
            h1, wsT, b_s, g_s, be_s, m_s, v_s, h2, t_base, TS, TSeff);
    }

    k_qconv<<<dim3(NU, B), 256, 0, stream>>>(h2, wcT, b_c, g_c, be_c, m_c, v_c, E);
    k_wins<<<B * F, 256, 0, stream>>>(E, S);
    k_fc<<<B, 256, 0, stream>>>(S, w_fc, b_fc, out);
}

// Round 4
// 210.102 us; speedup vs baseline: 1.4871x; 1.3479x over previous
//
#include <hip/hip_runtime.h>

#define EPS 1e-5f
#define B 16
#define CH 22
#define T_IN 1001
#define F 36
#define RF 65
#define T1 937            // T_IN - RF + 1
#define FC 792            // F*CH
#define KSPLIT 4
#define FCH 198           // FC/KSPLIT
#define FSPLIT 2
#define FH 18             // F/FSPLIT
#define UN 885            // valid u range for Q/E
#define UT 64             // K2 u-tile
#define NU 14             // ceil(885/64)
#define PS_LEN 106        // UT-1 + 3*14 + 1
#define KS 15
#define GN 295
#define WN 129
#define M43 43

// workspace float offsets
#define H2P_OFF 0                 // 4*16*36*937  = 2158848
#define EP_OFF  2158848           // + 2*16*36*885 = 1019520
#define S_OFF   3178368           // + 16*36*43    = 24768
#define WTT_OFF 3203136           // + 36*65       = 2340
#define WST_OFF 3205476           // + 792*36      = 28512
#define WCT_OFF 3233988           // + 36*15*36    = 19440
#define H1_OFF  3253440           // h1 (slabbed if scratch is tight)

__device__ __forceinline__ float elu_f(float v) {
    return v > 0.f ? v : (__expf(v) - 1.f);
}

// ---- prep: transpose weights for wave-uniform scalar access ---------------
__global__ __launch_bounds__(256) void k_prep(
    const float* __restrict__ w_t, const float* __restrict__ w_s,
    const float* __restrict__ w_c, float* __restrict__ wtT,
    float* __restrict__ wsT, float* __restrict__ wcT)
{
    int i = blockIdx.x * 256 + threadIdx.x;
    if (i < F * RF)     { int k = i / F,  fi = i % F; wtT[i] = w_t[fi * RF + k]; }
    if (i < FC * F)     { int fc = i / F, fo = i % F; wsT[i] = w_s[fo * FC + fc]; }
    if (i < F * KS * F) { int fk = i / F, fo = i % F; int f = fk / KS, k = fk % KS;
                          wcT[i] = w_c[(fo * F + f) * KS + k]; }
}

// ---- K1a: temporal conv + bn + elu -> h1[b][fc][t] (slab) -----------------
// grid (ntw, CH, B); 256 thr = 4 waves; wave = 9 fi x 64 t (lane = t)
__global__ __launch_bounds__(256) void k_tconv(
    const float* __restrict__ x,   const float* __restrict__ wtT,
    const float* __restrict__ b_t, const float* __restrict__ g_t,
    const float* __restrict__ be_t,const float* __restrict__ m_t,
    const float* __restrict__ v_t, float* __restrict__ h1,
    int t_base, int TS, int TSeff)
{
    const int lane = threadIdx.x & 63;
    const int fi0  = __builtin_amdgcn_readfirstlane((threadIdx.x >> 6) * 9);
    const int b = blockIdx.z, ch = blockIdx.y;
    const int tloc = blockIdx.x * 64 + lane;
    const int t  = t_base + tloc;
    const int tc = t < (T1 - 1) ? t : (T1 - 1);
    const float* xr = x + (b * CH + ch) * T_IN + tc;

    float acc[9];
    #pragma unroll
    for (int j = 0; j < 9; ++j) acc[j] = 0.f;

    #pragma unroll 5
    for (int k = 0; k < RF; ++k) {
        float xv = xr[k];
        const float* wr = wtT + k * F + fi0;
        #pragma unroll
        for (int j = 0; j < 9; ++j) acc[j] += xv * wr[j];
    }

    if (t < T1 && tloc < TSeff) {
        #pragma unroll
        for (int j = 0; j < 9; ++j) {
            int fi = fi0 + j;
            float s1 = g_t[fi] * rsqrtf(v_t[fi] + EPS);
            float o1 = (b_t[fi] - m_t[fi]) * s1 + be_t[fi];
            h1[((size_t)(b * F + fi) * CH + ch) * TS + tloc] =
                elu_f(acc[j] * s1 + o1);
        }
    }
}

// ---- K1b: 1x1 spatial conv, split-K over fc -> raw partials h2p -----------
// grid (ntw, KSPLIT, B); 256 thr = 4 waves; wave = 9 fo x 64 t (lane = t)
__global__ __launch_bounds__(256) void k_sconv(
    const float* __restrict__ h1,  const float* __restrict__ wsT,
    float* __restrict__ h2p, int t_base, int TS, int TSeff)
{
    const int lane = threadIdx.x & 63;
    const int fo0  = __builtin_amdgcn_readfirstlane((threadIdx.x >> 6) * 9);
    const int slice = blockIdx.y, b = blockIdx.z;
    const int tloc = blockIdx.x * 64 + lane;
    const int tlc  = tloc < (TSeff - 1) ? tloc : (TSeff - 1);
    const float* hr = h1 + ((size_t)b * FC + slice * FCH) * TS + tlc;
    const float* wb = wsT + slice * FCH * F;

    float acc[9];
    #pragma unroll
    for (int j = 0; j < 9; ++j) acc[j] = 0.f;

    #pragma unroll 9
    for (int fc = 0; fc < FCH; ++fc) {
        float hv = hr[(size_t)fc * TS];
        const float* wr = wb + fc * F + fo0;
        #pragma unroll
        for (int j = 0; j < 9; ++j) acc[j] += hv * wr[j];
    }

    int t = t_base + tloc;
    if (tloc < TSeff && t < T1) {
        #pragma unroll
        for (int j = 0; j < 9; ++j)
            h2p[(((size_t)slice * B + b) * F + fo0 + j) * T1 + t] = acc[j];
    }
}

// ---- K2: combine h2p + bn_s + elu + pool -> Ps; dilated conv -> Ep --------
// grid (NU, FSPLIT, B); 256 thr = 4 waves; wave = 9 fo x 64 u (lane = u)
__global__ __launch_bounds__(256) void k_qconv(
    const float* __restrict__ h2p, const float* __restrict__ wcT,
    const float* __restrict__ b_s, const float* __restrict__ g_s,
    const float* __restrict__ be_s,const float* __restrict__ m_s,
    const float* __restrict__ v_s, float* __restrict__ Ep)
{
    __shared__ float Ps[FH * PS_LEN];   // 7.6 KB
    const int tid = threadIdx.x;
    const int slice = blockIdx.y, b = blockIdx.z;
    const int u0 = blockIdx.x * UT;
    const int f_base = slice * FH;

    for (int i = tid; i < FH * PS_LEN; i += 256) {
        int fl = i / PS_LEN, j = i % PS_LEN;
        int f = f_base + fl;
        int s = u0 + j;
        float s2 = g_s[f] * rsqrtf(v_s[f] + EPS);
        float o2 = (b_s[f] - m_s[f]) * s2 + be_s[f];
        const float* p0 = h2p + ((size_t)(0 * B + b) * F + f) * T1;
        const float* p1 = h2p + ((size_t)(1 * B + b) * F + f) * T1;
        const float* p2 = h2p + ((size_t)(2 * B + b) * F + f) * T1;
        const float* p3 = h2p + ((size_t)(3 * B + b) * F + f) * T1;
        float a = 0.f;
        #pragma unroll
        for (int d = 0; d < 3; ++d) {
            int sp = s + d;
            if (sp < T1) {
                float q = p0[sp] + p1[sp] + p2[sp] + p3[sp];
                a += elu_f(q * s2 + o2);
            }
        }
        Ps[i] = a * (1.f / 3.f);
    }
    __syncthreads();

    const int u   = tid & 63;
    const int fo0 = __builtin_amdgcn_readfirstlane((tid >> 6) * 9);

    float acc[9];
    #pragma unroll
    for (int j = 0; j < 9; ++j) acc[j] = 0.f;

    for (int fl = 0; fl < FH; ++fl) {
        const int pb = fl * PS_LEN + u;
        const int f  = f_base + fl;
        #pragma unroll
        for (int k = 0; k < KS; ++k) {
            float pv = Ps[pb + 3 * k];
            const float* wr = wcT + (f * KS + k) * F + fo0;
            #pragma unroll
            for (int j = 0; j < 9; ++j) acc[j] += pv * wr[j];
        }
    }
    int u_g = u0 + u;
    if (u_g < UN) {
        #pragma unroll
        for (int j = 0; j < 9; ++j)
            Ep[(((size_t)slice * B + b) * F + fo0 + j) * UN + u_g] = acc[j];
    }
}

// ---- K3: combine Ep + bias + bn_c + elu, window sums -> S -----------------
__global__ __launch_bounds__(256) void k_wins(
    const float* __restrict__ Ep,  const float* __restrict__ b_c,
    const float* __restrict__ g_c, const float* __restrict__ be_c,
    const float* __restrict__ m_c, const float* __restrict__ v_c,
    float* __restrict__ S)
{
    __shared__ float Es[UN];
    __shared__ float G[GN];
    __shared__ float Ws[WN];
    const int tid = threadIdx.x;
    const int bf = blockIdx.x;
    const int f = bf % F;
    const float sc = g_c[f] * rsqrtf(v_c[f] + EPS);
    const float oc = (b_c[f] - m_c[f]) * sc + be_c[f];
    const float* e0 = Ep + (size_t)bf * UN;
    const float* e1 = Ep + ((size_t)B * F + bf) * UN;
    for (int i = tid; i < UN; i += 256)
        Es[i] = elu_f((e0[i] + e1[i]) * sc + oc);
    __syncthreads();
    for (int q = tid; q < GN; q += 256)
        G[q] = Es[3 * q] + Es[3 * q + 1] + Es[3 * q + 2];
    __syncthreads();
    if (tid < WN) {
        float a = 0.f;
        for (int q = tid; q < tid + 167; ++q) a += G[q];
        Ws[tid] = a;
    }
    __syncthreads();
    if (tid < M43)
        S[bf * M43 + tid] = (Ws[3 * tid] + Ws[3 * tid + 1] + Ws[3 * tid + 2]) * (1.f / 3.f);
}

// ---- K4: FC over summed features ------------------------------------------
__global__ __launch_bounds__(256) void k_fc(
    const float* __restrict__ S, const float* __restrict__ w_fc,
    const float* __restrict__ b_fc, float* __restrict__ out)
{
    const int b = blockIdx.x;
    const int o = threadIdx.x >> 6;
    const int lane = threadIdx.x & 63;
    float acc = 0.f;
    for (int n = lane; n < F * M43; n += 64)
        acc += w_fc[o * (F * M43) + n] * S[b * (F * M43) + n];
    #pragma unroll
    for (int off = 32; off > 0; off >>= 1)
        acc += __shfl_down(acc, off, 64);
    if (lane == 0) out[b * 4 + o] = acc * (1.f / 501.f) + b_fc[o];
}

extern "C" void kernel_launch(void* const* d_in, const int* in_sizes, int n_in,
                              void* d_out, int out_size, void* d_ws, size_t ws_size,
                              hipStream_t stream) {
    const float* x    = (const float*)d_in[0];
    const float* w_t  = (const float*)d_in[1];
    const float* b_t  = (const float*)d_in[2];
    const float* g_t  = (const float*)d_in[3];
    const float* be_t = (const float*)d_in[4];
    const float* m_t  = (const float*)d_in[5];
    const float* v_t  = (const float*)d_in[6];
    const float* w_s  = (const float*)d_in[7];
    const float* b_s  = (const float*)d_in[8];
    const float* g_s  = (const float*)d_in[9];
    const float* be_s = (const float*)d_in[10];
    const float* m_s  = (const float*)d_in[11];
    const float* v_s  = (const float*)d_in[12];
    const float* w_c  = (const float*)d_in[13];
    const float* b_c  = (const float*)d_in[14];
    const float* g_c  = (const float*)d_in[15];
    const float* be_c = (const float*)d_in[16];
    const float* m_c  = (const float*)d_in[17];
    const float* v_c  = (const float*)d_in[18];
    const float* w_fc = (const float*)d_in[19];
    const float* b_fc = (const float*)d_in[20];

    float* ws  = (float*)d_ws;
    float* h2p = ws + H2P_OFF;
    float* Ep  = ws + EP_OFF;
    float* S   = ws + S_OFF;
    float* wtT = ws + WTT_OFF;
    float* wsT = ws + WST_OFF;
    float* wcT = ws + WCT_OFF;
    float* h1  = ws + H1_OFF;
    float* out = (float*)d_out;

    // slab the t-dimension so h1 fits whatever scratch we actually have
    long long availF = (long long)(ws_size / 4) - (long long)H1_OFF;
    long long tsl = availF / (B * FC);
    int TS;
    if (tsl >= T1) TS = T1;
    else { TS = (int)(tsl & ~63LL); if (TS < 64) TS = 64; }
    int nslab = (T1 + TS - 1) / TS;

    k_prep<<<dim3(112), 256, 0, stream>>>(w_t, w_s, w_c, wtT, wsT, wcT);

    for (int sl = 0; sl < nslab; ++sl) {
        int t_base = sl * TS;
        int TSeff = T1 - t_base; if (TSeff > TS) TSeff = TS;
        int ntw = (TSeff + 63) / 64;
        k_tconv<<<dim3(ntw, CH, B), 256, 0, stream>>>(
            x, wtT, b_t, g_t, be_t, m_t, v_t, h1, t_base, TS, TSeff);
        k_sconv<<<dim3(ntw, KSPLIT, B), 256, 0, stream>>>(
            h1, wsT, h2p, t_base, TS, TSeff);
    }

    k_qconv<<<dim3(NU, FSPLIT, B), 256, 0, stream>>>(
        h2p, wcT, b_s, g_s, be_s, m_s, v_s, Ep);
    k_wins<<<B * F, 256, 0, stream>>>(Ep, b_c, g_c, be_c, m_c, v_c, S);
    k_fc<<<B, 256, 0, stream>>>(S, w_fc, b_fc, out);
}